// Round 5
// baseline (39.830 us; speedup 1.0000x reference)
//
#include <hip/hip_runtime.h>

#define NN 32
#define MAX_ITERS 10
#define RPT 4                   // rows per thread, depth-1 software pipeline
#define TPB 256

// Projection math validated R1-R3 (bit-exact algebraic form of reference):
//  forward = 31-step prefix-min; backward: q[u] = med3(p[u], max_child, q_fwd[u-1]).
__device__ __forceinline__ void project_row(const float4 a[8], float4 o[8]) {
    float p[NN], q[NN];
    #pragma unroll
    for (int k = 0; k < 8; ++k) {
        p[4*k+0] = a[k].x; p[4*k+1] = a[k].y;
        p[4*k+2] = a[k].z; p[4*k+3] = a[k].w;
    }
    #pragma unroll
    for (int i = 0; i < NN; ++i) {
        float e = __expf(-p[i]);
        p[i] = __builtin_amdgcn_rcpf(1.0f + e);   // sigmoid, 1 ulp
        q[i] = p[i];
    }
    for (int it = 0; it < MAX_ITERS; ++it) {
        #pragma unroll
        for (int u = 0; u < NN - 1; ++u)
            q[u + 1] = fminf(q[u + 1], q[u]);
        #pragma unroll
        for (int u = NN - 1; u >= 0; --u) {
            float maxc;
            if (u == NN - 1)      maxc = 0.0f;
            else if (u == NN - 2) maxc = q[NN - 1];
            else                  maxc = fmaxf(q[u + 1], q[u + 2]);
            float minp = (u == 0) ? 1.0f : q[u - 1];
            q[u] = __builtin_amdgcn_fmed3f(p[u], maxc, minp);
        }
    }
    #pragma unroll
    for (int k = 0; k < 8; ++k)
        o[k] = make_float4(q[4*k+0], q[4*k+1], q[4*k+2], q[4*k+3]);
}

// Depth-1 pipeline over RPT grid-stride rows. The asm memory fence pins the
// prefetch loads ABOVE the compute+store (R3's version lacked it and the
// compiler sank the loads to their use -- VGPR_Count 52 proved it). With the
// fence, compute on row r waits only vmcnt(8) while row r+1's loads remain in
// flight; stores drain under the next row's compute. rr-loop left rolled so
// the ~10 KB body stays I-cache resident.
__global__ __launch_bounds__(TPB) void dag_constraint_kernel(
    const float* __restrict__ x, float* __restrict__ out, int brows)
{
    const int tid = blockIdx.x * blockDim.x + threadIdx.x;
    const int stride = gridDim.x * blockDim.x;
    const float4* __restrict__ xg = reinterpret_cast<const float4*>(x);
    float4* __restrict__ og = reinterpret_cast<float4*>(out);

    float4 a[8], b[8];
    long long r = tid;
    if (r < brows) {
        #pragma unroll
        for (int k = 0; k < 8; ++k) a[k] = xg[r * 8 + k];
    }

    for (int rr = 0; rr < RPT; ++rr) {
        const long long rn = r + stride;

        // prefetch next row
        if (rr + 1 < RPT && rn < brows) {
            #pragma unroll
            for (int k = 0; k < 8; ++k) b[k] = xg[rn * 8 + k];
        }

        // compiler-level fence: prefetch loads may not sink below, stores may
        // not hoist above. Keeps b's loads in flight across the compute.
        asm volatile("" ::: "memory");

        if (r < brows) {
            float4 o[8];
            project_row(a, o);                    // waits vmcnt(8) -> a only
            #pragma unroll
            for (int k = 0; k < 8; ++k) og[r * 8 + k] = o[k];  // fire-and-forget
        }

        #pragma unroll
        for (int k = 0; k < 8; ++k) a[k] = b[k];
        r = rn;
    }
}

extern "C" void kernel_launch(void* const* d_in, const int* in_sizes, int n_in,
                              void* d_out, int out_size, void* d_ws, size_t ws_size,
                              hipStream_t stream)
{
    const float* x = (const float*)d_in[0];
    float* out = (float*)d_out;

    int total = in_sizes[0];      // B * N
    int brows = total / NN;       // B rows

    int threads_needed = (brows + RPT - 1) / RPT;      // 131072
    int blocks = (threads_needed + TPB - 1) / TPB;     // 512 -> 2 blocks/CU

    dag_constraint_kernel<<<blocks, TPB, 0, stream>>>(x, out, brows);
}

// Round 6
// 37.087 us; speedup vs baseline: 1.0739x; 1.0739x over previous
//
#include <hip/hip_runtime.h>

#define NN 32
#define MAX_ITERS 10
#define TPB 256

// DAG projection, graph compile-time constant (children u+1,u+2; parents u-1,u-2).
// Algebraic form validated R1-R5 (bit-exact vs reference scans):
//   forward  = 31-step prefix-min
//   backward = q[u] = med3(p[u], max(q[u+1],q[u+2]), q_fwd[u-1])
//
// __launch_bounds__(256, 4): min 4 waves/EU -> 128 unified-reg cap. Forces the
// allocator to keep p[32]+q[32] in architectural VGPRs instead of the default
// occupancy-chasing split (VGPR_Count 36-52 in R0-R5 with 64+ floats live =>
// AGPR-banked state + v_accvgpr_read/write on every scan-chain access).
// 4 waves/SIMD also covers the serial fwd/bwd dependency chains.
__global__ __launch_bounds__(TPB, 4) void dag_constraint_kernel(
    const float* __restrict__ x, float* __restrict__ out, int brows)
{
    const int row = blockIdx.x * blockDim.x + threadIdx.x;
    if (row >= brows) return;

    const float4* __restrict__ xr =
        reinterpret_cast<const float4*>(x) + (size_t)row * (NN / 4);

    float p[NN], q[NN];
    #pragma unroll
    for (int k = 0; k < NN / 4; ++k) {
        float4 v = xr[k];
        p[4*k+0] = v.x; p[4*k+1] = v.y; p[4*k+2] = v.z; p[4*k+3] = v.w;
    }

    // sigmoid via v_exp + v_rcp (1 ulp; error << 0.0198 threshold)
    #pragma unroll
    for (int i = 0; i < NN; ++i) {
        float e = __expf(-p[i]);
        p[i] = __builtin_amdgcn_rcpf(1.0f + e);
        q[i] = p[i];
    }

    // Keep the iteration loop rolled: ~1 KB body stays I$-resident; iterations
    // are serially dependent so unrolling adds no ILP.
    #pragma unroll 1
    for (int it = 0; it < MAX_ITERS; ++it) {
        #pragma unroll
        for (int u = 0; u < NN - 1; ++u)
            q[u + 1] = fminf(q[u + 1], q[u]);

        #pragma unroll
        for (int u = NN - 1; u >= 0; --u) {
            float maxc;
            if (u == NN - 1)      maxc = 0.0f;
            else if (u == NN - 2) maxc = q[NN - 1];
            else                  maxc = fmaxf(q[u + 1], q[u + 2]);
            float minp = (u == 0) ? 1.0f : q[u - 1];
            q[u] = __builtin_amdgcn_fmed3f(p[u], maxc, minp);
        }
    }

    float4* __restrict__ outr =
        reinterpret_cast<float4*>(out) + (size_t)row * (NN / 4);
    #pragma unroll
    for (int k = 0; k < NN / 4; ++k)
        outr[k] = make_float4(q[4*k+0], q[4*k+1], q[4*k+2], q[4*k+3]);
}

extern "C" void kernel_launch(void* const* d_in, const int* in_sizes, int n_in,
                              void* d_out, int out_size, void* d_ws, size_t ws_size,
                              hipStream_t stream)
{
    const float* x = (const float*)d_in[0];
    float* out = (float*)d_out;

    int total = in_sizes[0];      // B * N
    int brows = total / NN;       // B rows

    int blocks = (brows + TPB - 1) / TPB;   // 2048
    dag_constraint_kernel<<<blocks, TPB, 0, stream>>>(x, out, brows);
}

// Round 7
// 36.977 us; speedup vs baseline: 1.0771x; 1.0030x over previous
//
#include <hip/hip_runtime.h>

#define NN 32
#define MAX_ITERS 10
#define TPB 256

// DAG projection, graph compile-time constant (children u+1,u+2; parents u-1,u-2).
// Algebraic form validated R1-R6 (bit-exact vs reference scans):
//   forward  = 31-step prefix-min
//   backward = q[u] = med3(p[u], max(q[u+1],q[u+2]), q_fwd[u-1])
//
// amdgpu_waves_per_eu(4,4): clamp the allocator's occupancy TARGET to 4
// waves/EU (128-reg budget). launch_bounds' 2nd arg only sets the minimum
// (a reg cap); the default heuristic still chased 8 waves/EU (~64-reg budget)
// and AGPR-banked half of p[32]+q[32] (VGPR_Count=36 in R1/R6 with 64+ floats
// live), paying v_accvgpr_read/write inside the serial scan chains --
// VALUBusy*dur ~= 2x the hand-counted issue time in every round. 4 waves/SIMD
// x ~50% issue demand still saturates the VALU pipe.
__global__ __launch_bounds__(TPB)
__attribute__((amdgpu_waves_per_eu(4, 4)))
void dag_constraint_kernel(
    const float* __restrict__ x, float* __restrict__ out, int brows)
{
    const int row = blockIdx.x * blockDim.x + threadIdx.x;
    if (row >= brows) return;

    const float4* __restrict__ xr =
        reinterpret_cast<const float4*>(x) + (size_t)row * (NN / 4);

    float p[NN], q[NN];
    #pragma unroll
    for (int k = 0; k < NN / 4; ++k) {
        float4 v = xr[k];
        p[4*k+0] = v.x; p[4*k+1] = v.y; p[4*k+2] = v.z; p[4*k+3] = v.w;
    }

    // sigmoid via v_exp + v_rcp (1 ulp; error << 0.0198 threshold)
    #pragma unroll
    for (int i = 0; i < NN; ++i) {
        float e = __expf(-p[i]);
        p[i] = __builtin_amdgcn_rcpf(1.0f + e);
        q[i] = p[i];
    }

    // Iteration loop rolled: ~1 KB body stays I$-resident; iterations are
    // serially dependent so unrolling adds no ILP.
    #pragma unroll 1
    for (int it = 0; it < MAX_ITERS; ++it) {
        #pragma unroll
        for (int u = 0; u < NN - 1; ++u)
            q[u + 1] = fminf(q[u + 1], q[u]);

        #pragma unroll
        for (int u = NN - 1; u >= 0; --u) {
            float maxc;
            if (u == NN - 1)      maxc = 0.0f;
            else if (u == NN - 2) maxc = q[NN - 1];
            else                  maxc = fmaxf(q[u + 1], q[u + 2]);
            float minp = (u == 0) ? 1.0f : q[u - 1];
            q[u] = __builtin_amdgcn_fmed3f(p[u], maxc, minp);
        }
    }

    float4* __restrict__ outr =
        reinterpret_cast<float4*>(out) + (size_t)row * (NN / 4);
    #pragma unroll
    for (int k = 0; k < NN / 4; ++k)
        outr[k] = make_float4(q[4*k+0], q[4*k+1], q[4*k+2], q[4*k+3]);
}

extern "C" void kernel_launch(void* const* d_in, const int* in_sizes, int n_in,
                              void* d_out, int out_size, void* d_ws, size_t ws_size,
                              hipStream_t stream)
{
    const float* x = (const float*)d_in[0];
    float* out = (float*)d_out;

    int total = in_sizes[0];      // B * N
    int brows = total / NN;       // B rows

    int blocks = (brows + TPB - 1) / TPB;   // 2048
    dag_constraint_kernel<<<blocks, TPB, 0, stream>>>(x, out, brows);
}